// Round 13
// baseline (490.186 us; speedup 1.0000x reference)
//
#include <hip/hip_runtime.h>
#include <hip/hip_bf16.h>
#include <string.h>

// Batched GEMM: out[b,o,f] = sum_i W[b,o,i] * x[b,i,f]
// B=32, M(O)=1024, K(I)=1024, N(F)=2048, fp32 in/out, bf16 MFMA compute.
//
// Round-13: P/C v3. Same as r12 except PRIORITY INVERTED:
//   producers run at s_setprio(1)  (long latency chain; tiny issue demand)
//   consumers at default prio 0    (MFMA pipe is issue-delay tolerant)
// r12's consumer-side setprio(1) starved the producer of issue slots during
// the MFMA window, serializing P and C phases (dur 2x, both utils halved).
// 768 thr = 4 producer + 8 consumer waves; per SIMD 1P+2C (508<=512 regs).
// 256x256 tile, BK=32, LSTR=36 (<=2-way banks, 6.3e6 conflicts measured),
// double buffer, lgkm-only barrier per K-step, producer loads one K-step
// ahead, XCD-chunked block swizzle.

typedef float  f32x2 __attribute__((ext_vector_type(2)));
typedef float  f32x4 __attribute__((ext_vector_type(4)));
typedef short  bf16x8 __attribute__((ext_vector_type(8)));
typedef unsigned int u32;

#define BATCH 32
#define MDIM 1024
#define KDIM 1024
#define NDIM 2048
#define BM 256
#define BN 256
#define BK 32
#define NT (KDIM / BK)   // 32 K-steps
#define LSTR 36          // ushorts per LDS row: 32 data + 4 pad (18 banks)

__device__ __forceinline__ u32 cvt2(float a, float b) {
    float2 t; t.x = a; t.y = b;
    __hip_bfloat162 h = __float22bfloat162_rn(t);   // v_cvt_pk_bf16_f32 (RTNE)
    u32 r; memcpy(&r, &h, 4);
    return r;
}

// Barrier that does NOT drain vmcnt: LDS visibility only.
__device__ __forceinline__ void lds_barrier() {
    asm volatile("s_waitcnt lgkmcnt(0)" ::: "memory");
    __builtin_amdgcn_s_barrier();
    asm volatile("" ::: "memory");
}

__global__ __launch_bounds__(768, 3) void bgemm_pc_kernel(
    const float* __restrict__ x, const float* __restrict__ w,
    float* __restrict__ out)
{
    __shared__ unsigned short Ab[2][BM * LSTR];   // W tile  [m][k]
    __shared__ unsigned short Bb[2][BN * LSTR];   // x tile^T [n][k]  (73.7 KB)

    // ---- XCD-chunked bijective block swizzle (1024 blocks, 1024%8==0) ----
    const int bid  = blockIdx.x;
    const int lbid = (bid & 7) * 128 + (bid >> 3);
    const int bx = lbid & 7;          // n-tile
    const int by = (lbid >> 3) & 3;   // m-tile
    const int bz = lbid >> 5;         // batch

    const int tid  = threadIdx.x;
    const int wid  = tid >> 6;
    const int lane = tid & 63;

    const float* Ag = w + (size_t)bz * MDIM * KDIM + (size_t)(by * BM) * KDIM;
    const float* Bg = x + (size_t)bz * KDIM * NDIM + bx * BN;

    if (wid < 4) {
        // ================= PRODUCERS (256 threads) =================
        __builtin_amdgcn_s_setprio(1);   // keep staging fed under consumer MFMA
        // A: thread -> rows (tid>>3)+32i (i=0..7), f32x4 col tid&7
        const int a_k4 = tid & 7;
        const int a_m0 = tid >> 3;        // 0..31
        int a_idx[8];
        #pragma unroll
        for (int i = 0; i < 8; ++i)
            a_idx[i] = (a_m0 + 32 * i) * LSTR + 4 * a_k4;
        // B: thread -> 2 n-cols (2*(tid&127)+c), 16 k-rows (16*(tid>>7)+j)
        const int bn0  = 2 * (tid & 127);
        const int b_k0 = 16 * (tid >> 7);   // 0 or 16
        int b_idx[2];
        #pragma unroll
        for (int c = 0; c < 2; ++c)
            b_idx[c] = (bn0 + c) * LSTR + b_k0;

        const float* Ap = Ag + (size_t)a_m0 * KDIM + 4 * a_k4;
        const float* Bp = Bg + (size_t)b_k0 * NDIM + bn0;

        f32x4 aav[8];
        f32x2 bbv[16];
        auto load_regs = [&](int kt) {
            #pragma unroll
            for (int i = 0; i < 8; ++i)
                aav[i] = *reinterpret_cast<const f32x4*>(
                    Ap + (size_t)(32 * i) * KDIM + kt);
            #pragma unroll
            for (int j = 0; j < 16; ++j)
                bbv[j] = *reinterpret_cast<const f32x2*>(
                    Bp + (size_t)(kt + j) * NDIM);
        };
        auto stage = [&](int s) {
            #pragma unroll
            for (int i = 0; i < 8; ++i) {
                uint2 v = make_uint2(cvt2(aav[i][0], aav[i][1]),
                                     cvt2(aav[i][2], aav[i][3]));
                *reinterpret_cast<uint2*>(&Ab[s][a_idx[i]]) = v;   // ds_write_b64
            }
            #pragma unroll
            for (int c = 0; c < 2; ++c) {
                uint4 v0 = make_uint4(cvt2(bbv[0][c],  bbv[1][c]),
                                      cvt2(bbv[2][c],  bbv[3][c]),
                                      cvt2(bbv[4][c],  bbv[5][c]),
                                      cvt2(bbv[6][c],  bbv[7][c]));
                *reinterpret_cast<uint4*>(&Bb[s][b_idx[c]]) = v0;      // k 0-7
                uint4 v1 = make_uint4(cvt2(bbv[8][c],  bbv[9][c]),
                                      cvt2(bbv[10][c], bbv[11][c]),
                                      cvt2(bbv[12][c], bbv[13][c]),
                                      cvt2(bbv[14][c], bbv[15][c]));
                *reinterpret_cast<uint4*>(&Bb[s][b_idx[c] + 8]) = v1;  // k 8-15
            }
        };

        load_regs(0);
        stage(0);
        load_regs(BK);          // tile 1 loads in flight across barrier[0]
        lds_barrier();          // barrier[0]
        for (int t = 1; t < NT; ++t) {
            stage(t & 1);       // regs loaded one full K-step ago -> no stall
            if (t + 1 < NT)
                load_regs((t + 1) * BK);
            lds_barrier();      // barrier[t]
        }
        // producers exit
    } else {
        // ================= CONSUMERS (512 threads, 8 waves) =================
        const int cw  = wid - 4;
        const int wm  = (cw >> 1) * 64;    // wave tile 64x128
        const int wn  = (cw & 1) * 128;
        const int l15 = lane & 15;
        const int kg8 = (lane >> 4) * 8;

        int rd_a[4], rd_b[8];
        #pragma unroll
        for (int mi = 0; mi < 4; ++mi)
            rd_a[mi] = (wm + mi * 16 + l15) * LSTR + kg8;
        #pragma unroll
        for (int ni = 0; ni < 8; ++ni)
            rd_b[ni] = (wn + ni * 16 + l15) * LSTR + kg8;

        f32x4 acc[4][8];
        #pragma unroll
        for (int i = 0; i < 4; ++i)
            #pragma unroll
            for (int j = 0; j < 8; ++j)
                acc[i][j] = f32x4{0.f, 0.f, 0.f, 0.f};

        lds_barrier();          // barrier[0]: tile 0 ready
        for (int t = 0; t < NT; ++t) {
            const int s = t & 1;
            bf16x8 af[4];
            #pragma unroll
            for (int mi = 0; mi < 4; ++mi)
                af[mi] = *reinterpret_cast<const bf16x8*>(&Ab[s][rd_a[mi]]);
            #pragma unroll
            for (int ni = 0; ni < 8; ++ni) {
                bf16x8 bfr = *reinterpret_cast<const bf16x8*>(&Bb[s][rd_b[ni]]);
                #pragma unroll
                for (int mi = 0; mi < 4; ++mi)
                    acc[mi][ni] = __builtin_amdgcn_mfma_f32_16x16x32_bf16(
                        af[mi], bfr, acc[mi][ni], 0, 0, 0);
            }
            if (t < NT - 1) lds_barrier();   // barriers[1..NT-1]
        }

        // ---- C store: D layout col=lane&15, row=(lane>>4)*4+reg ----
        float* Cg = out + (size_t)bz * MDIM * NDIM
                        + (size_t)(by * BM) * NDIM + bx * BN;
        const int rbase = (lane >> 4) * 4;
        #pragma unroll
        for (int mi = 0; mi < 4; ++mi) {
            #pragma unroll
            for (int ni = 0; ni < 8; ++ni) {
                int n  = wn + ni * 16 + l15;
                int mb = wm + mi * 16 + rbase;
                #pragma unroll
                for (int r = 0; r < 4; ++r)
                    Cg[(size_t)(mb + r) * NDIM + n] = acc[mi][ni][r];
            }
        }
    }
}

extern "C" void kernel_launch(void* const* d_in, const int* in_sizes, int n_in,
                              void* d_out, int out_size, void* d_ws, size_t ws_size,
                              hipStream_t stream) {
    const float* x = (const float*)d_in[0];   // [32][1024][2048]
    const float* w = (const float*)d_in[1];   // [32][1024][1024]
    float* out = (float*)d_out;               // [32][1024][2048]
    const int nblocks = (NDIM / BN) * (MDIM / BM) * BATCH;  // 8*4*32 = 1024
    bgemm_pc_kernel<<<dim3(nblocks), dim3(768), 0, stream>>>(x, w, out);
}

// Round 14
// 346.071 us; speedup vs baseline: 1.4164x; 1.4164x over previous
//
#include <hip/hip_runtime.h>
#include <hip/hip_bf16.h>
#include <string.h>

// Batched GEMM: out[b,o,f] = sum_i W[b,o,i] * x[b,i,f]
// B=32, M(O)=1024, K(I)=1024, N(F)=2048, fp32 in/out.
//
// Round-14: two-stage. K1a converts W -> bf16 [m][k]; K1b transpose-converts
// x -> bf16 [n][k] (both into d_ws). K2 is a pure-bf16 256x256 GEMM with
// global_load_lds staging and a 4-phase counted-vmcnt schedule (m201-style):
// per K-step(64): ph1{rd A(kk0,mi0-3)+B(kk0); stage A-kk0(t+1)} ph2{rd
// A(kk0,mi4-7); stage B-kk0; vmcnt(4)} ph3{rd kk1 ...; stage A-kk1}
// ph4{...; stage B-kk1; vmcnt(4)}; each phase: BAR; setprio; 16 MFMA; BAR.
// LDS [kk][256 rows][32 k] (64B rows), XOR swizzle on the *source* chunk
// (linear gload_lds dest) + same XOR on frag reads -> <=2-way banks.
// Falls back to the r8 reg-staged kernel if ws_size < 192MB.

typedef float  f32x2 __attribute__((ext_vector_type(2)));
typedef float  f32x4 __attribute__((ext_vector_type(4)));
typedef short  bf16x8 __attribute__((ext_vector_type(8)));
typedef unsigned int u32;
typedef unsigned short u16;

#define BATCH 32
#define MDIM 1024
#define KDIM 1024
#define NDIM 2048

__device__ __forceinline__ u32 cvt2(float a, float b) {
    float2 t; t.x = a; t.y = b;
    __hip_bfloat162 h = __float22bfloat162_rn(t);   // v_cvt_pk_bf16_f32 (RTNE)
    u32 r; memcpy(&r, &h, 4);
    return r;
}

// ===========================================================================
// K1a: W fp32 [32][1024][1024] -> bf16 same layout
// ===========================================================================
__global__ __launch_bounds__(256) void conv_w_kernel(
    const float* __restrict__ w, u16* __restrict__ wb)
{
    const int nt = gridDim.x * blockDim.x;
    const int total = BATCH * MDIM * KDIM / 4;   // 8388608 f32x4
    for (int i = blockIdx.x * blockDim.x + threadIdx.x; i < total; i += nt) {
        f32x4 v = *reinterpret_cast<const f32x4*>(w + (size_t)i * 4);
        uint2 p = make_uint2(cvt2(v[0], v[1]), cvt2(v[2], v[3]));
        *reinterpret_cast<uint2*>(wb + (size_t)i * 4) = p;
    }
}

// ===========================================================================
// K1b: x fp32 [32][1024 k][2048 n] -> bf16 x' [32][2048 n][1024 k] (transpose)
// 64x64 tiles via LDS.
// ===========================================================================
__global__ __launch_bounds__(256) void conv_xt_kernel(
    const float* __restrict__ x, u16* __restrict__ xb)
{
    __shared__ u16 tl[64][72];    // [n'][k'], stride 72 (16B-aligned rows)

    const int bz = blockIdx.z;
    const int k0 = blockIdx.y * 64;
    const int n0 = blockIdx.x * 64;
    const int t  = threadIdx.x;
    const int a  = t >> 4;        // k-group 0..15
    const int b  = t & 15;        // n-group 0..15

    f32x4 v[4];
    #pragma unroll
    for (int i = 0; i < 4; ++i)
        v[i] = *reinterpret_cast<const f32x4*>(
            x + ((size_t)(bz * KDIM + k0 + 4 * a + i)) * NDIM + n0 + 4 * b);

    #pragma unroll
    for (int j = 0; j < 4; ++j) {
        uint2 p = make_uint2(cvt2(v[0][j], v[1][j]), cvt2(v[2][j], v[3][j]));
        *reinterpret_cast<uint2*>(&tl[4 * b + j][4 * a]) = p;
    }
    __syncthreads();

    const int rn = t >> 2;        // 0..63
    const int q  = t & 3;         // 16-ushort chunk
    u16* dst = xb + ((size_t)(bz * NDIM + n0 + rn)) * KDIM + k0 + 16 * q;
    *reinterpret_cast<uint4*>(dst)     = *reinterpret_cast<uint4*>(&tl[rn][16 * q]);
    *reinterpret_cast<uint4*>(dst + 8) = *reinterpret_cast<uint4*>(&tl[rn][16 * q + 8]);
}

// ===========================================================================
// K2: bf16 GEMM. A = W' [m][k], B = x' [n][k]. 256x256 tile, BK=64, 512 thr.
// ===========================================================================
#define BM 256
#define BN 256
#define BK 64
#define NT2 (KDIM / BK)    // 16

typedef __attribute__((address_space(1))) const unsigned char glob_u8;
typedef __attribute__((address_space(3))) unsigned char lds_u8;

__device__ __forceinline__ void gload16(const void* g, void* l) {
    __builtin_amdgcn_global_load_lds((glob_u8*)g, (lds_u8*)l, 16, 0, 0);
}

__global__ __launch_bounds__(512, 2) void bgemm_4ph_kernel(
    const u16* __restrict__ xb, const u16* __restrict__ wb,
    float* __restrict__ out)
{
    // per buf: [2 kk][256 rows][32 k] ushorts = 16384
    __shared__ u16 Al[2][16384];
    __shared__ u16 Bl[2][16384];

    // XCD-chunked bijective block swizzle (1024 blocks)
    const int bid  = blockIdx.x;
    const int lbid = (bid & 7) * 128 + (bid >> 3);
    const int bx = lbid & 7;          // n-tile
    const int by = (lbid >> 3) & 3;   // m-tile
    const int bz = lbid >> 5;         // batch

    const int tid  = threadIdx.x;
    const int wid  = tid >> 6;
    const int lane = tid & 63;
    const int wm   = (wid >> 2) * 128;   // wave tile 128x64
    const int wn   = (wid & 3)  * 64;
    const int l15  = lane & 15;
    const int h    = lane >> 4;          // k-chunk within kk-half (0..3)

    const int m0 = by * BM;
    const int n0 = bx * BN;

    const u16* Wb = wb + ((size_t)bz << 20);   // [1024][1024]
    const u16* Xb = xb + ((size_t)bz << 21);   // [2048][1024]

    // ---- staging source bases (per wave-instr i=0,1; swizzled chunk) ----
    const int srow = wid * 32 + (lane >> 2);           // + i*16
    const int ssw  = 8 * ((lane & 3) ^ ((lane >> 2) & 3));
    const u16* aSrc[2];
    const u16* bSrc[2];
    #pragma unroll
    for (int i = 0; i < 2; ++i) {
        aSrc[i] = Wb + (size_t)(m0 + srow + i * 16) * KDIM + ssw;
        bSrc[i] = Xb + (size_t)(n0 + srow + i * 16) * KDIM + ssw;
    }
    const int ldst0 = wid * 1024 + 0 * 512;   // ushort idx of instr 0 dest
    const int ldst1 = wid * 1024 + 1 * 512;

    // ---- frag read indices ----
    int rdA[2][8], rdB[2][4];
    #pragma unroll
    for (int kk = 0; kk < 2; ++kk) {
        #pragma unroll
        for (int mi = 0; mi < 8; ++mi) {
            int m = wm + mi * 16 + l15;
            rdA[kk][mi] = kk * 8192 + m * 32 + 8 * (h ^ (m & 3));
        }
        #pragma unroll
        for (int ni = 0; ni < 4; ++ni) {
            int n = wn + ni * 16 + l15;
            rdB[kk][ni] = kk * 8192 + n * 32 + 8 * (h ^ (n & 3));
        }
    }

    f32x4 acc[8][4];
    #pragma unroll
    for (int i = 0; i < 8; ++i)
        #pragma unroll
        for (int j = 0; j < 4; ++j)
            acc[i][j] = f32x4{0.f, 0.f, 0.f, 0.f};

    auto stageA = [&](int sb, int q, int kt) {
        gload16(aSrc[0] + kt + q * 32, &Al[sb][q * 8192 + ldst0]);
        gload16(aSrc[1] + kt + q * 32, &Al[sb][q * 8192 + ldst1]);
    };
    auto stageB = [&](int sb, int q, int kt) {
        gload16(bSrc[0] + kt + q * 32, &Bl[sb][q * 8192 + ldst0]);
        gload16(bSrc[1] + kt + q * 32, &Bl[sb][q * 8192 + ldst1]);
    };

    // ---- prologue: stage tile 0 into buf0, oldest-first kk0 then kk1 ----
    stageA(0, 0, 0);
    stageB(0, 0, 0);
    stageA(0, 1, 0);
    stageB(0, 1, 0);
    asm volatile("s_waitcnt vmcnt(4)" ::: "memory");   // tile0-kk0 landed
    __builtin_amdgcn_s_barrier();

    for (int t = 0; t < NT2; ++t) {
        const int s   = t & 1;
        const int sx  = s ^ 1;
        const int ktn = (t + 1) * BK;
        const bool st = (t + 1 < NT2);
        bf16x8 afr[4], bfr[4];

        // ===== ph1: kk0, mi0-3 (+B kk0); stage A-kk0(t+1) =====
        #pragma unroll
        for (int ni = 0; ni < 4; ++ni)
            bfr[ni] = *reinterpret_cast<const bf16x8*>(&Bl[s][rdB[0][ni]]);
        #pragma unroll
        for (int mi = 0; mi < 4; ++mi)
            afr[mi] = *reinterpret_cast<const bf16x8*>(&Al[s][rdA[0][mi]]);
        if (st) stageA(sx, 0, ktn);
        __builtin_amdgcn_s_barrier();
        __builtin_amdgcn_s_setprio(1);
        #pragma unroll
        for (int mi = 0; mi < 4; ++mi)
            #pragma unroll
            for (int ni = 0; ni < 4; ++ni)
                acc[mi][ni] = __builtin_amdgcn_mfma_f32_16x16x32_bf16(
                    afr[mi], bfr[ni], acc[mi][ni], 0, 0, 0);
        __builtin_amdgcn_s_setprio(0);
        __builtin_amdgcn_s_barrier();

        // ===== ph2: kk0, mi4-7; stage B-kk0(t+1); vmcnt =====
        #pragma unroll
        for (int mi = 0; mi < 4; ++mi)
            afr[mi] = *reinterpret_cast<const bf16x8*>(&Al[s][rdA[0][mi + 4]]);
        if (st) stageB(sx, 0, ktn);
        if (t == NT2 - 1)
            asm volatile("s_waitcnt vmcnt(0)" ::: "memory");
        else
            asm volatile("s_waitcnt vmcnt(4)" ::: "memory");
        __builtin_amdgcn_s_barrier();
        __builtin_amdgcn_s_setprio(1);
        #pragma unroll
        for (int mi = 0; mi < 4; ++mi)
            #pragma unroll
            for (int ni = 0; ni < 4; ++ni)
                acc[mi + 4][ni] = __builtin_amdgcn_mfma_f32_16x16x32_bf16(
                    afr[mi], bfr[ni], acc[mi + 4][ni], 0, 0, 0);
        __builtin_amdgcn_s_setprio(0);
        __builtin_amdgcn_s_barrier();

        // ===== ph3: kk1, mi0-3 (+B kk1); stage A-kk1(t+1) =====
        #pragma unroll
        for (int ni = 0; ni < 4; ++ni)
            bfr[ni] = *reinterpret_cast<const bf16x8*>(&Bl[s][rdB[1][ni]]);
        #pragma unroll
        for (int mi = 0; mi < 4; ++mi)
            afr[mi] = *reinterpret_cast<const bf16x8*>(&Al[s][rdA[1][mi]]);
        if (st) stageA(sx, 1, ktn);
        __builtin_amdgcn_s_barrier();
        __builtin_amdgcn_s_setprio(1);
        #pragma unroll
        for (int mi = 0; mi < 4; ++mi)
            #pragma unroll
            for (int ni = 0; ni < 4; ++ni)
                acc[mi][ni] = __builtin_amdgcn_mfma_f32_16x16x32_bf16(
                    afr[mi], bfr[ni], acc[mi][ni], 0, 0, 0);
        __builtin_amdgcn_s_setprio(0);
        __builtin_amdgcn_s_barrier();

        // ===== ph4: kk1, mi4-7; stage B-kk1(t+1); vmcnt(4) =====
        #pragma unroll
        for (int mi = 0; mi < 4; ++mi)
            afr[mi] = *reinterpret_cast<const bf16x8*>(&Al[s][rdA[1][mi + 4]]);
        if (st) stageB(sx, 1, ktn);
        asm volatile("s_waitcnt vmcnt(4)" ::: "memory");
        __builtin_amdgcn_s_barrier();
        __builtin_amdgcn_s_setprio(1);
        #pragma unroll
        for (int mi = 0; mi < 4; ++mi)
            #pragma unroll
            for (int ni = 0; ni < 4; ++ni)
                acc[mi + 4][ni] = __builtin_amdgcn_mfma_f32_16x16x32_bf16(
                    afr[mi], bfr[ni], acc[mi + 4][ni], 0, 0, 0);
        __builtin_amdgcn_s_setprio(0);
        __builtin_amdgcn_s_barrier();
    }

    // ---- C store: D layout col=lane&15, row=(lane>>4)*4+reg ----
    float* Cg = out + (size_t)bz * MDIM * NDIM + (size_t)(m0)*NDIM + n0;
    const int rbase = (lane >> 4) * 4;
    #pragma unroll
    for (int mi = 0; mi < 8; ++mi) {
        #pragma unroll
        for (int ni = 0; ni < 4; ++ni) {
            int n  = wn + ni * 16 + l15;
            int mb = wm + mi * 16 + rbase;
            #pragma unroll
            for (int r = 0; r < 4; ++r)
                Cg[(size_t)(mb + r) * NDIM + n] = acc[mi][ni][r];
        }
    }
}

// ===========================================================================
// FALLBACK (r8): reg-staged 2-phase, used when ws_size < 192MB
// ===========================================================================
#define FLSTR 68

__device__ __forceinline__ void lds_barrier() {
    asm volatile("s_waitcnt lgkmcnt(0)" ::: "memory");
    __builtin_amdgcn_s_barrier();
    asm volatile("" ::: "memory");
}

__global__ __launch_bounds__(512, 2) void bgemm_fb_kernel(
    const float* __restrict__ x, const float* __restrict__ w,
    float* __restrict__ out)
{
    __shared__ u16 Ab[2][BM * FLSTR];
    __shared__ u16 Bb[2][BN * FLSTR];

    const int bid  = blockIdx.x;
    const int lbid = (bid & 7) * 128 + (bid >> 3);
    const int bx = lbid & 7, by = (lbid >> 3) & 3, bz = lbid >> 5;
    const int tid = threadIdx.x, lane = tid & 63, wid = tid >> 6;
    const int wm = (wid >> 2) * 128, wn = (wid & 3) * 64;
    const int l15 = lane & 15, kg8 = (lane >> 4) * 8;

    const float* Ag = w + (size_t)bz * MDIM * KDIM + (size_t)(by * BM) * KDIM;
    const float* Bg = x + (size_t)bz * KDIM * NDIM + bx * BN;
    float* Cg = out + (size_t)bz * MDIM * NDIM + (size_t)(by * BM) * NDIM + bx * BN;

    const int a_k4 = tid & 15, a_m0 = tid >> 4;
    int a_idx[8];
    #pragma unroll
    for (int i = 0; i < 8; ++i) a_idx[i] = (a_m0 + 32 * i) * FLSTR + 4 * a_k4;
    const int bn0 = 2 * (tid & 127), b_k0 = 8 * (tid >> 7);
    int b_idx[2];
    #pragma unroll
    for (int c = 0; c < 2; ++c) b_idx[c] = (bn0 + c) * FLSTR + b_k0;
    int rd_a[8], rd_b[4];
    #pragma unroll
    for (int mi = 0; mi < 8; ++mi) rd_a[mi] = (wm + mi * 16 + l15) * FLSTR + kg8;
    #pragma unroll
    for (int ni = 0; ni < 4; ++ni) rd_b[ni] = (wn + ni * 16 + l15) * FLSTR + kg8;

    const float* Ap = Ag + (size_t)a_m0 * KDIM + 4 * a_k4;
    const float* Bp = Bg + (size_t)b_k0 * NDIM + bn0;

    f32x4 acc[8][4];
    #pragma unroll
    for (int i = 0; i < 8; ++i)
        #pragma unroll
        for (int j = 0; j < 4; ++j) acc[i][j] = f32x4{0.f, 0.f, 0.f, 0.f};

    f32x4 aav[4]; f32x2 bbv[8];
    auto load_regs = [&](int kt, int hh) {
        #pragma unroll
        for (int i = 0; i < 4; ++i)
            aav[i] = *reinterpret_cast<const f32x4*>(Ap + (size_t)(32 * (i + 4 * hh)) * KDIM + kt);
        #pragma unroll
        for (int j = 0; j < 8; ++j)
            bbv[j] = *reinterpret_cast<const f32x2*>(Bp + (size_t)(kt + 32 * hh + j) * NDIM);
    };
    auto stage = [&](int s, int hh) {
        #pragma unroll
        for (int i = 0; i < 4; ++i) {
            uint2 v = make_uint2(cvt2(aav[i][0], aav[i][1]), cvt2(aav[i][2], aav[i][3]));
            *reinterpret_cast<uint2*>(&Ab[s][a_idx[i + 4 * hh]]) = v;
        }
        #pragma unroll
        for (int c = 0; c < 2; ++c) {
            uint4 v = make_uint4(cvt2(bbv[0][c], bbv[1][c]), cvt2(bbv[2][c], bbv[3][c]),
                                 cvt2(bbv[4][c], bbv[5][c]), cvt2(bbv[6][c], bbv[7][c]));
            *reinterpret_cast<uint4*>(&Bb[s][b_idx[c] + 32 * hh]) = v;
        }
    };
    auto mfma_half = [&](int s, int kk, int mb) {
        bf16x8 bfr[4], af[4];
        #pragma unroll
        for (int ni = 0; ni < 4; ++ni)
            bfr[ni] = *reinterpret_cast<const bf16x8*>(&Bb[s][rd_b[ni] + 32 * kk]);
        #pragma unroll
        for (int mi = 0; mi < 4; ++mi)
            af[mi] = *reinterpret_cast<const bf16x8*>(&Ab[s][rd_a[mi + mb] + 32 * kk]);
        #pragma unroll
        for (int mi = 0; mi < 4; ++mi)
            #pragma unroll
            for (int ni = 0; ni < 4; ++ni)
                acc[mi + mb][ni] = __builtin_amdgcn_mfma_f32_16x16x32_bf16(
                    af[mi], bfr[ni], acc[mi + mb][ni], 0, 0, 0);
    };

    load_regs(0, 0); stage(0, 0); load_regs(0, 1); stage(0, 1); load_regs(BK, 0);
    lds_barrier();
    for (int t = 0; t < NT2 - 1; ++t) {
        const int cur = t & 1;
        stage(cur ^ 1, 0);
        load_regs((t + 1) * BK, 1);
        mfma_half(cur, 0, 0); mfma_half(cur, 0, 4);
        stage(cur ^ 1, 1);
        int kt2 = (t + 2) * BK; if (kt2 > KDIM - BK) kt2 = KDIM - BK;
        load_regs(kt2, 0);
        mfma_half(cur, 1, 0); mfma_half(cur, 1, 4);
        lds_barrier();
    }
    {
        const int cur = (NT2 - 1) & 1;
        mfma_half(cur, 0, 0); mfma_half(cur, 0, 4);
        mfma_half(cur, 1, 0); mfma_half(cur, 1, 4);
    }
    const int rbase = (lane >> 4) * 4;
    #pragma unroll
    for (int mi = 0; mi < 8; ++mi)
        #pragma unroll
        for (int ni = 0; ni < 4; ++ni) {
            int n = wn + ni * 16 + l15, mb = wm + mi * 16 + rbase;
            #pragma unroll
            for (int r = 0; r < 4; ++r)
                Cg[(size_t)(mb + r) * NDIM + n] = acc[mi][ni][r];
        }
}

// ===========================================================================
extern "C" void kernel_launch(void* const* d_in, const int* in_sizes, int n_in,
                              void* d_out, int out_size, void* d_ws, size_t ws_size,
                              hipStream_t stream) {
    const float* x = (const float*)d_in[0];   // [32][1024][2048]
    const float* w = (const float*)d_in[1];   // [32][1024][1024]
    float* out = (float*)d_out;               // [32][1024][2048]

    const size_t need = (size_t)BATCH * MDIM * KDIM * 2      // W' 64MB
                      + (size_t)BATCH * NDIM * KDIM * 2;     // x' 128MB
    if (ws_size >= need) {
        u16* wb = (u16*)d_ws;                                 // [32][1024][1024]
        u16* xb = wb + (size_t)BATCH * MDIM * KDIM;           // [32][2048][1024]
        conv_w_kernel<<<dim3(2048), dim3(256), 0, stream>>>(w, wb);
        conv_xt_kernel<<<dim3(NDIM / 64, KDIM / 64, BATCH), dim3(256), 0, stream>>>(x, xb);
        bgemm_4ph_kernel<<<dim3((NDIM / BN) * (MDIM / BM) * BATCH), dim3(512), 0, stream>>>(xb, wb, out);
    } else {
        bgemm_fb_kernel<<<dim3((NDIM / BN) * (MDIM / BM) * BATCH), dim3(512), 0, stream>>>(x, w, out);
    }
}

// Round 15
// 343.997 us; speedup vs baseline: 1.4250x; 1.0060x over previous
//
#include <hip/hip_runtime.h>
#include <hip/hip_bf16.h>
#include <string.h>

// Batched GEMM: out[b,o,f] = sum_i W[b,o,i] * x[b,i,f]
// B=32, M(O)=1024, K(I)=1024, N(F)=2048, fp32 in/out.
//
// Round-15 two-stage, v2:
//  K1a: W fp32 -> bf16, relayout to chunk-major tiles [b][my][k/8][m][8]
//  K1b: x fp32 -> bf16, transpose+relayout to [b][nx][k/8][n][8]
//  K2: 256x256 GEMM, BK=32, 512 thr, triple-buffered LDS (96KB),
//      global_load_lds staging (linear, coalesced), ONE barrier/K-step,
//      counted vmcnt(4) (never 0 mid-loop), zero-conflict frag reads by
//      layout construction (consecutive 16B chunks per 16-lane phase).
// Fallback: r8 reg-staged kernel if ws_size too small.

typedef float  f32x2 __attribute__((ext_vector_type(2)));
typedef float  f32x4 __attribute__((ext_vector_type(4)));
typedef short  bf16x8 __attribute__((ext_vector_type(8)));
typedef unsigned int u32;
typedef unsigned short u16;

#define BATCH 32
#define MDIM 1024
#define KDIM 1024
#define NDIM 2048

__device__ __forceinline__ u32 cvt2(float a, float b) {
    float2 t; t.x = a; t.y = b;
    __hip_bfloat162 h = __float22bfloat162_rn(t);   // v_cvt_pk_bf16_f32 (RTNE)
    u32 r; memcpy(&r, &h, 4);
    return r;
}

// ===========================================================================
// K1a: W [32][1024 m][1024 k] fp32 -> ws chunks: region (b*4+my) of 32768
// chunks; chunk ((k/8)*256 + m%256) holds bf16 W[m][8k], 16B each.
// Block: 64m x 64k tile, 256 threads.
// ===========================================================================
__global__ __launch_bounds__(256) void conv_w_kernel(
    const float* __restrict__ w, u16* __restrict__ wb)
{
    __shared__ u16 tl[64][72];
    const int bz = blockIdx.z;
    const int gy = blockIdx.y;           // m-tile64: 0..15
    const int t64 = blockIdx.x;          // k-tile64: 0..15
    const int tid = threadIdx.x;
    const int my  = gy >> 2;
    const int mbase = (gy & 3) * 64;
    const int gm0 = gy * 64;
    const int k0  = t64 * 64;

    const int ml = tid >> 2;             // 0..63
    const int c  = tid & 3;
    const float* src = w + (size_t)bz * MDIM * KDIM + (size_t)(gm0 + ml) * KDIM + k0 + 16 * c;
    f32x4 v[4];
    #pragma unroll
    for (int i = 0; i < 4; ++i)
        v[i] = *reinterpret_cast<const f32x4*>(src + 4 * i);
    #pragma unroll
    for (int i = 0; i < 4; ++i) {
        uint2 p = make_uint2(cvt2(v[i][0], v[i][1]), cvt2(v[i][2], v[i][3]));
        *reinterpret_cast<uint2*>(&tl[ml][16 * c + 4 * i]) = p;
    }
    __syncthreads();

    const int q  = tid >> 5;             // k8-group in tile: 0..7
    const int mm = (tid & 31) * 2;
    u16* dst = wb + ((size_t)(bz * 4 + my) << 18)
                  + ((size_t)((t64 * 8 + q) * 256 + mbase + mm) << 3);
    *reinterpret_cast<uint4*>(dst)     = *reinterpret_cast<uint4*>(&tl[mm][8 * q]);
    *reinterpret_cast<uint4*>(dst + 8) = *reinterpret_cast<uint4*>(&tl[mm + 1][8 * q]);
}

// ===========================================================================
// K1b: x [32][1024 k][2048 n] fp32 -> ws chunks: region (b*8+nx) of 32768
// chunks; chunk ((k/8)*256 + n%256) holds bf16 x[k..k+8][n] (k-contig, 16B).
// Block: 64k x 64n tile, 256 threads (transpose via LDS).
// ===========================================================================
__global__ __launch_bounds__(256) void conv_xt_kernel(
    const float* __restrict__ x, u16* __restrict__ xb)
{
    __shared__ u16 tl[64][72];           // [n_local][k_local]
    const int bz  = blockIdx.z;
    const int t64 = blockIdx.y;          // k-tile64: 0..15
    const int gx  = blockIdx.x;          // n-tile64: 0..31
    const int tid = threadIdx.x;
    const int nx    = gx >> 2;
    const int nbase = (gx & 3) * 64;
    const int n0g   = gx * 64;
    const int k0    = t64 * 64;

    const int a = tid >> 4;              // k-group 0..15
    const int b = tid & 15;              // n-group 0..15
    f32x4 v[4];
    #pragma unroll
    for (int i = 0; i < 4; ++i)
        v[i] = *reinterpret_cast<const f32x4*>(
            x + (size_t)(bz * KDIM + k0 + 4 * a + i) * NDIM + n0g + 4 * b);
    #pragma unroll
    for (int j = 0; j < 4; ++j) {
        uint2 p = make_uint2(cvt2(v[0][j], v[1][j]), cvt2(v[2][j], v[3][j]));
        *reinterpret_cast<uint2*>(&tl[4 * b + j][4 * a]) = p;
    }
    __syncthreads();

    const int q  = tid >> 5;             // 0..7
    const int nn = (tid & 31) * 2;
    u16* dst = xb + ((size_t)(bz * 8 + nx) << 18)
                  + ((size_t)((t64 * 8 + q) * 256 + nbase + nn) << 3);
    *reinterpret_cast<uint4*>(dst)     = *reinterpret_cast<uint4*>(&tl[nn][8 * q]);
    *reinterpret_cast<uint4*>(dst + 8) = *reinterpret_cast<uint4*>(&tl[nn + 1][8 * q]);
}

// ===========================================================================
// K2: 256x256 tile, BK=32, 512 thr, 8 waves (wave 128x64), triple buffer.
// ===========================================================================
#define BM 256
#define BN 256
#define BK2 32
#define NT32 (KDIM / BK2)   // 32

typedef __attribute__((address_space(1))) const unsigned char glob_u8;
typedef __attribute__((address_space(3))) unsigned char lds_u8;

__device__ __forceinline__ void gload16(const void* g, void* l) {
    __builtin_amdgcn_global_load_lds((glob_u8*)g, (lds_u8*)l, 16, 0, 0);
}

__global__ __launch_bounds__(512, 2) void bgemm_3buf_kernel(
    const u16* __restrict__ xb, const u16* __restrict__ wb,
    float* __restrict__ out)
{
    __shared__ u16 Al[3][8192];   // per buf: 1024 chunks = 32KB; A total 48KB
    __shared__ u16 Bl[3][8192];   // B total 48KB; grand total 96KB

    // XCD-chunked bijective block swizzle (1024 blocks)
    const int bid  = blockIdx.x;
    const int lbid = (bid & 7) * 128 + (bid >> 3);
    const int bx = lbid & 7;          // n-tile
    const int by = (lbid >> 3) & 3;   // m-tile
    const int bz = lbid >> 5;         // batch

    const int tid  = threadIdx.x;
    const int wid  = tid >> 6;
    const int lane = tid & 63;
    const int wm   = (wid >> 2) * 128;
    const int wn   = (wid & 3)  * 64;
    const int l15  = lane & 15;
    const int h    = lane >> 4;       // k8-group 0..3

    const u16* baseA = wb + ((size_t)(bz * 4 + by) << 18);
    const u16* baseB = xb + ((size_t)(bz * 8 + bx) << 18);

    // frag read ushort indices (chunk-major: chunk = h*256 + row)
    int rdA[8], rdB[4];
    #pragma unroll
    for (int mi = 0; mi < 8; ++mi)
        rdA[mi] = (h * 256 + wm + mi * 16 + l15) * 8;
    #pragma unroll
    for (int ni = 0; ni < 4; ++ni)
        rdB[ni] = (h * 256 + wn + ni * 16 + l15) * 8;

    f32x4 acc[8][4];
    #pragma unroll
    for (int i = 0; i < 8; ++i)
        #pragma unroll
        for (int j = 0; j < 4; ++j)
            acc[i][j] = f32x4{0.f, 0.f, 0.f, 0.f};

    auto stage = [&](int t, int s) {
        #pragma unroll
        for (int i = 0; i < 2; ++i) {
            gload16(baseA + ((size_t)t * 1024 + i * 512 + tid) * 8,
                    &Al[s][(i * 512 + tid) * 8]);
            gload16(baseB + ((size_t)t * 1024 + i * 512 + tid) * 8,
                    &Bl[s][(i * 512 + tid) * 8]);
        }
    };

    // prologue: tiles 0 and 1 in flight (8 outstanding)
    stage(0, 0);
    stage(1, 1);

    for (int t = 0; t < NT32; ++t) {
        const int s = t % 3;
        if (t < NT32 - 1)
            asm volatile("s_waitcnt vmcnt(4)" ::: "memory");   // tile t landed
        else
            asm volatile("s_waitcnt vmcnt(0)" ::: "memory");
        __builtin_amdgcn_s_barrier();     // all waves have tile t; buf[(t+2)%3] free
        if (t + 2 < NT32)
            stage(t + 2, (t + 2) % 3);    // 8 outstanding again

        // compute tile t (stable buffer; no further sync needed)
        bf16x8 bfr[4];
        #pragma unroll
        for (int ni = 0; ni < 4; ++ni)
            bfr[ni] = *reinterpret_cast<const bf16x8*>(&Bl[s][rdB[ni]]);
        __builtin_amdgcn_s_setprio(1);
        #pragma unroll
        for (int mi = 0; mi < 8; ++mi) {
            bf16x8 af = *reinterpret_cast<const bf16x8*>(&Al[s][rdA[mi]]);
            #pragma unroll
            for (int ni = 0; ni < 4; ++ni)
                acc[mi][ni] = __builtin_amdgcn_mfma_f32_16x16x32_bf16(
                    af, bfr[ni], acc[mi][ni], 0, 0, 0);
        }
        __builtin_amdgcn_s_setprio(0);
    }

    // C store: D layout col=lane&15, row=(lane>>4)*4+reg
    float* Cg = out + (size_t)bz * MDIM * NDIM
                    + (size_t)(by * BM) * NDIM + bx * BN;
    const int rbase = (lane >> 4) * 4;
    #pragma unroll
    for (int mi = 0; mi < 8; ++mi) {
        #pragma unroll
        for (int ni = 0; ni < 4; ++ni) {
            int n  = wn + ni * 16 + l15;
            int mb = wm + mi * 16 + rbase;
            #pragma unroll
            for (int r = 0; r < 4; ++r)
                Cg[(size_t)(mb + r) * NDIM + n] = acc[mi][ni][r];
        }
    }
}

// ===========================================================================
// FALLBACK (r8): reg-staged 2-phase, used when ws_size < 192MB
// ===========================================================================
#define FBK 64
#define FNT (KDIM / FBK)
#define FLSTR 68

__device__ __forceinline__ void lds_barrier() {
    asm volatile("s_waitcnt lgkmcnt(0)" ::: "memory");
    __builtin_amdgcn_s_barrier();
    asm volatile("" ::: "memory");
}

__global__ __launch_bounds__(512, 2) void bgemm_fb_kernel(
    const float* __restrict__ x, const float* __restrict__ w,
    float* __restrict__ out)
{
    __shared__ u16 Ab[2][BM * FLSTR];
    __shared__ u16 Bb[2][BN * FLSTR];

    const int bid  = blockIdx.x;
    const int lbid = (bid & 7) * 128 + (bid >> 3);
    const int bx = lbid & 7, by = (lbid >> 3) & 3, bz = lbid >> 5;
    const int tid = threadIdx.x, lane = tid & 63, wid = tid >> 6;
    const int wm = (wid >> 2) * 128, wn = (wid & 3) * 64;
    const int l15 = lane & 15, kg8 = (lane >> 4) * 8;

    const float* Ag = w + (size_t)bz * MDIM * KDIM + (size_t)(by * BM) * KDIM;
    const float* Bg = x + (size_t)bz * KDIM * NDIM + bx * BN;
    float* Cg = out + (size_t)bz * MDIM * NDIM + (size_t)(by * BM) * NDIM + bx * BN;

    const int a_k4 = tid & 15, a_m0 = tid >> 4;
    int a_idx[8];
    #pragma unroll
    for (int i = 0; i < 8; ++i) a_idx[i] = (a_m0 + 32 * i) * FLSTR + 4 * a_k4;
    const int bn0 = 2 * (tid & 127), b_k0 = 8 * (tid >> 7);
    int b_idx[2];
    #pragma unroll
    for (int c = 0; c < 2; ++c) b_idx[c] = (bn0 + c) * FLSTR + b_k0;
    int rd_a[8], rd_b[4];
    #pragma unroll
    for (int mi = 0; mi < 8; ++mi) rd_a[mi] = (wm + mi * 16 + l15) * FLSTR + kg8;
    #pragma unroll
    for (int ni = 0; ni < 4; ++ni) rd_b[ni] = (wn + ni * 16 + l15) * FLSTR + kg8;

    const float* Ap = Ag + (size_t)a_m0 * KDIM + 4 * a_k4;
    const float* Bp = Bg + (size_t)b_k0 * NDIM + bn0;

    f32x4 acc[8][4];
    #pragma unroll
    for (int i = 0; i < 8; ++i)
        #pragma unroll
        for (int j = 0; j < 4; ++j) acc[i][j] = f32x4{0.f, 0.f, 0.f, 0.f};

    f32x4 aav[4]; f32x2 bbv[8];
    auto load_regs = [&](int kt, int hh) {
        #pragma unroll
        for (int i = 0; i < 4; ++i)
            aav[i] = *reinterpret_cast<const f32x4*>(Ap + (size_t)(32 * (i + 4 * hh)) * KDIM + kt);
        #pragma unroll
        for (int j = 0; j < 8; ++j)
            bbv[j] = *reinterpret_cast<const f32x2*>(Bp + (size_t)(kt + 32 * hh + j) * NDIM);
    };
    auto stage = [&](int s, int hh) {
        #pragma unroll
        for (int i = 0; i < 4; ++i) {
            uint2 v = make_uint2(cvt2(aav[i][0], aav[i][1]), cvt2(aav[i][2], aav[i][3]));
            *reinterpret_cast<uint2*>(&Ab[s][a_idx[i + 4 * hh]]) = v;
        }
        #pragma unroll
        for (int c = 0; c < 2; ++c) {
            uint4 v = make_uint4(cvt2(bbv[0][c], bbv[1][c]), cvt2(bbv[2][c], bbv[3][c]),
                                 cvt2(bbv[4][c], bbv[5][c]), cvt2(bbv[6][c], bbv[7][c]));
            *reinterpret_cast<uint4*>(&Bb[s][b_idx[c] + 32 * hh]) = v;
        }
    };
    auto mfma_half = [&](int s, int kk, int mb) {
        bf16x8 bfr[4], af[4];
        #pragma unroll
        for (int ni = 0; ni < 4; ++ni)
            bfr[ni] = *reinterpret_cast<const bf16x8*>(&Bb[s][rd_b[ni] + 32 * kk]);
        #pragma unroll
        for (int mi = 0; mi < 4; ++mi)
            af[mi] = *reinterpret_cast<const bf16x8*>(&Ab[s][rd_a[mi + mb] + 32 * kk]);
        #pragma unroll
        for (int mi = 0; mi < 4; ++mi)
            #pragma unroll
            for (int ni = 0; ni < 4; ++ni)
                acc[mi + mb][ni] = __builtin_amdgcn_mfma_f32_16x16x32_bf16(
                    af[mi], bfr[ni], acc[mi + mb][ni], 0, 0, 0);
    };

    load_regs(0, 0); stage(0, 0); load_regs(0, 1); stage(0, 1); load_regs(FBK, 0);
    lds_barrier();
    for (int t = 0; t < FNT - 1; ++t) {
        const int cur = t & 1;
        stage(cur ^ 1, 0);
        load_regs((t + 1) * FBK, 1);
        mfma_half(cur, 0, 0); mfma_half(cur, 0, 4);
        stage(cur ^ 1, 1);
        int kt2 = (t + 2) * FBK; if (kt2 > KDIM - FBK) kt2 = KDIM - FBK;
        load_regs(kt2, 0);
        mfma_half(cur, 1, 0); mfma_half(cur, 1, 4);
        lds_barrier();
    }
    {
        const int cur = (FNT - 1) & 1;
        mfma_half(cur, 0, 0); mfma_half(cur, 0, 4);
        mfma_half(cur, 1, 0); mfma_half(cur, 1, 4);
    }
    const int rbase = (lane >> 4) * 4;
    #pragma unroll
    for (int mi = 0; mi < 8; ++mi)
        #pragma unroll
        for (int ni = 0; ni < 4; ++ni) {
            int n = wn + ni * 16 + l15, mb = wm + mi * 16 + rbase;
            #pragma unroll
            for (int r = 0; r < 4; ++r)
                Cg[(size_t)(mb + r) * NDIM + n] = acc[mi][ni][r];
        }
}

// ===========================================================================
extern "C" void kernel_launch(void* const* d_in, const int* in_sizes, int n_in,
                              void* d_out, int out_size, void* d_ws, size_t ws_size,
                              hipStream_t stream) {
    const float* x = (const float*)d_in[0];   // [32][1024][2048]
    const float* w = (const float*)d_in[1];   // [32][1024][1024]
    float* out = (float*)d_out;               // [32][1024][2048]

    const size_t need = (size_t)BATCH * MDIM * KDIM * 2
                      + (size_t)BATCH * NDIM * KDIM * 2;   // 192MB
    if (ws_size >= need) {
        u16* wb = (u16*)d_ws;
        u16* xb = wb + (size_t)BATCH * MDIM * KDIM;
        conv_w_kernel<<<dim3(16, 16, BATCH), dim3(256), 0, stream>>>(w, wb);
        conv_xt_kernel<<<dim3(32, 16, BATCH), dim3(256), 0, stream>>>(x, xb);
        bgemm_3buf_kernel<<<dim3((NDIM / BN) * (MDIM / BM) * BATCH), dim3(512), 0, stream>>>(xb, wb, out);
    } else {
        bgemm_fb_kernel<<<dim3((NDIM / BN) * (MDIM / BM) * BATCH), dim3(512), 0, stream>>>(x, w, out);
    }
}

// Round 16
// 250.644 us; speedup vs baseline: 1.9557x; 1.3725x over previous
//
#include <hip/hip_runtime.h>
#include <hip/hip_bf16.h>
#include <string.h>

// Batched GEMM: out[b,o,f] = sum_i W[b,o,i] * x[b,i,f]
// B=32, M(O)=1024, K(I)=1024, N(F)=2048, fp32 in/out, bf16 MFMA compute.
//
// Round-16: r8 geometry/schedule (256x256 tile, 512 thr, 8 waves, BK=64,
// LSTR=68, reg-staged cvt_pk -> LDS, double buffer, lgkm-only barrier,
// XCD swizzle, setprio) with MFMA 16x16x32 -> 32x32x16:
//  - 2382 vs 2075 TF ceiling (+15% FLOP/cy), half the MFMA + frag-read instrs
//  - wave tile 128x64 = 4x2 frags of 32x32, acc 8 x f32x16 = 128 AGPR (same)
//  - A frag: row=lane&31, k=8*(lane>>5)+j (k-contig b128); B symmetric
//  - C/D: col=lane&31, row=(reg&3)+8*(reg>>2)+4*(lane>>5)  [m74/m101]
// MFMA in 4 ks-quarters (8 MFMA each) to cap live frag regs at 24 VGPR.

typedef float  f32x2 __attribute__((ext_vector_type(2)));
typedef float  f32x4 __attribute__((ext_vector_type(4)));
typedef float  f32x16 __attribute__((ext_vector_type(16)));
typedef short  bf16x8 __attribute__((ext_vector_type(8)));
typedef unsigned int u32;

#define BATCH 32
#define MDIM 1024
#define KDIM 1024
#define NDIM 2048
#define BM 256
#define BN 256
#define BK 64
#define NT (KDIM / BK)   // 16 K-steps
#define LSTR 68          // ushorts per LDS row: 64 data + 4 pad (34 banks)

__device__ __forceinline__ u32 cvt2(float a, float b) {
    float2 t; t.x = a; t.y = b;
    __hip_bfloat162 h = __float22bfloat162_rn(t);   // v_cvt_pk_bf16_f32 (RTNE)
    u32 r; memcpy(&r, &h, 4);
    return r;
}

// Barrier that does NOT drain vmcnt: LDS visibility only.
__device__ __forceinline__ void lds_barrier() {
    asm volatile("s_waitcnt lgkmcnt(0)" ::: "memory");
    __builtin_amdgcn_s_barrier();
    asm volatile("" ::: "memory");
}

__global__ __launch_bounds__(512, 2) void bgemm_bf16_kernel(
    const float* __restrict__ x, const float* __restrict__ w,
    float* __restrict__ out)
{
    __shared__ unsigned short Ab[2][BM * LSTR];   // W tile  [m][k]
    __shared__ unsigned short Bb[2][BN * LSTR];   // x tile^T [n][k]

    // ---- XCD-chunked bijective block swizzle (1024 blocks, 1024%8==0) ----
    const int bid  = blockIdx.x;
    const int lbid = (bid & 7) * 128 + (bid >> 3);
    const int bx = lbid & 7;          // n-tile
    const int by = (lbid >> 3) & 3;   // m-tile
    const int bz = lbid >> 5;         // batch

    const int tid  = threadIdx.x;
    const int lane = tid & 63;
    const int wid  = tid >> 6;
    const int wm   = (wid >> 2) * 128;   // wave tile 128x64
    const int wn   = (wid & 3)  * 64;
    const int l31  = lane & 31;
    const int kg8  = (lane >> 5) * 8;    // k-offset within a 16-k step

    const float* Ag = w + (size_t)bz * MDIM * KDIM + (size_t)(by * BM) * KDIM;
    const float* Bg = x + (size_t)bz * KDIM * NDIM + bx * BN;
    float*       Cg = out + (size_t)bz * MDIM * NDIM
                          + (size_t)(by * BM) * NDIM + bx * BN;

    // ---- A staging map: thread -> rows (tid>>4)+32i (i=0..7), f32x4 col tid&15
    const int a_k4 = tid & 15;
    const int a_m0 = tid >> 4;           // 0..31
    int a_idx[8];
    #pragma unroll
    for (int i = 0; i < 8; ++i)
        a_idx[i] = (a_m0 + 32 * i) * LSTR + 4 * a_k4;
    // ---- B staging map: chunk h covers k rows 32h + 8*(tid>>7)+j, n cols 2*(tid&127)
    const int bn0  = 2 * (tid & 127);
    const int b_k0 = 8 * (tid >> 7);     // 0,8,16,24
    int b_idx[2];
    #pragma unroll
    for (int c = 0; c < 2; ++c)
        b_idx[c] = (bn0 + c) * LSTR + b_k0;
    // ---- frag read addrs: per frag row-base; k-offset 16*ks added at use ----
    int rd_a[4], rd_b[2];
    #pragma unroll
    for (int fm = 0; fm < 4; ++fm)
        rd_a[fm] = (wm + fm * 32 + l31) * LSTR + kg8;
    #pragma unroll
    for (int fn = 0; fn < 2; ++fn)
        rd_b[fn] = (wn + fn * 32 + l31) * LSTR + kg8;

    const float* Ap = Ag + (size_t)a_m0 * KDIM + 4 * a_k4;
    const float* Bp = Bg + (size_t)b_k0 * NDIM + bn0;

    f32x16 acc[8];   // [fm*2+fn]
    #pragma unroll
    for (int i = 0; i < 8; ++i)
        acc[i] = (f32x16)(0.f);

    f32x4 aav[4];
    f32x2 bbv[8];

    // ---- load sub-chunk h of K-step kt into regs ----
    auto load_regs = [&](int kt, int h) {
        #pragma unroll
        for (int i = 0; i < 4; ++i)
            aav[i] = *reinterpret_cast<const f32x4*>(
                Ap + (size_t)(32 * (i + 4 * h)) * KDIM + kt);
        #pragma unroll
        for (int j = 0; j < 8; ++j)
            bbv[j] = *reinterpret_cast<const f32x2*>(
                Bp + (size_t)(kt + 32 * h + j) * NDIM);
    };
    // ---- cvt + LDS write of reg sub-chunk h into buffer s ----
    auto stage = [&](int s, int h) {
        #pragma unroll
        for (int i = 0; i < 4; ++i) {
            uint2 v = make_uint2(cvt2(aav[i][0], aav[i][1]),
                                 cvt2(aav[i][2], aav[i][3]));
            *reinterpret_cast<uint2*>(&Ab[s][a_idx[i + 4 * h]]) = v; // b64
        }
        #pragma unroll
        for (int c = 0; c < 2; ++c) {
            uint4 v = make_uint4(cvt2(bbv[0][c], bbv[1][c]),
                                 cvt2(bbv[2][c], bbv[3][c]),
                                 cvt2(bbv[4][c], bbv[5][c]),
                                 cvt2(bbv[6][c], bbv[7][c]));
            *reinterpret_cast<uint4*>(&Bb[s][b_idx[c] + 32 * h]) = v; // b128
        }
    };
    // ---- one ks-quarter: 6 frag reads + 8 MFMA ----
    auto quarter = [&](int s, int ks) {
        bf16x8 af[4], bf[2];
        const int ko = 16 * ks;
        #pragma unroll
        for (int fn = 0; fn < 2; ++fn)
            bf[fn] = *reinterpret_cast<const bf16x8*>(&Bb[s][rd_b[fn] + ko]);
        #pragma unroll
        for (int fm = 0; fm < 4; ++fm)
            af[fm] = *reinterpret_cast<const bf16x8*>(&Ab[s][rd_a[fm] + ko]);
        __builtin_amdgcn_s_setprio(1);
        #pragma unroll
        for (int fm = 0; fm < 4; ++fm)
            #pragma unroll
            for (int fn = 0; fn < 2; ++fn)
                acc[fm * 2 + fn] = __builtin_amdgcn_mfma_f32_32x32x16_bf16(
                    af[fm], bf[fn], acc[fm * 2 + fn], 0, 0, 0);
        __builtin_amdgcn_s_setprio(0);
    };

    // ---- prologue: stage tile 0 fully, load (tile1, chunk0) ----
    load_regs(0, 0);
    stage(0, 0);
    load_regs(0, 1);
    stage(0, 1);
    load_regs(BK, 0);
    lds_barrier();

    // ---- main loop: compute tile t, stage tile t+1 ----
    for (int t = 0; t < NT - 1; ++t) {
        const int cur = t & 1;
        const int ktn = (t + 1) * BK;

        quarter(cur, 0);
        stage(cur ^ 1, 0);          // chunk0 of t+1 (regs loaded last iter)
        load_regs(ktn, 1);          // chunk1 -> regs
        quarter(cur, 1);
        quarter(cur, 2);
        stage(cur ^ 1, 1);          // chunk1 of t+1
        int kt2 = (t + 2) * BK;
        if (kt2 > KDIM - BK) kt2 = KDIM - BK;   // clamp (last value unused)
        load_regs(kt2, 0);          // next iter's chunk0
        quarter(cur, 3);

        lds_barrier();
    }

    // ---- tail: tile NT-1, no staging ----
    {
        const int cur = (NT - 1) & 1;
        #pragma unroll
        for (int ks = 0; ks < 4; ++ks)
            quarter(cur, ks);
    }

    // ---- C store: col=lane&31, row=(reg&3)+8*(reg>>2)+4*(lane>>5) ----
    const int rbase = 4 * (lane >> 5);
    #pragma unroll
    for (int fm = 0; fm < 4; ++fm) {
        #pragma unroll
        for (int fn = 0; fn < 2; ++fn) {
            const f32x16& a16 = acc[fm * 2 + fn];
            const int n = wn + fn * 32 + l31;
            #pragma unroll
            for (int r = 0; r < 16; ++r) {
                int row = wm + fm * 32 + (r & 3) + 8 * (r >> 2) + rbase;
                Cg[(size_t)row * NDIM + n] = a16[r];
            }
        }
    }
}

extern "C" void kernel_launch(void* const* d_in, const int* in_sizes, int n_in,
                              void* d_out, int out_size, void* d_ws, size_t ws_size,
                              hipStream_t stream) {
    const float* x = (const float*)d_in[0];   // [32][1024][2048]
    const float* w = (const float*)d_in[1];   // [32][1024][1024]
    float* out = (float*)d_out;               // [32][1024][2048]
    const int nblocks = (NDIM / BN) * (MDIM / BM) * BATCH;  // 8*4*32 = 1024
    bgemm_bf16_kernel<<<dim3(nblocks), dim3(512), 0, stream>>>(x, w, out);
}